// Round 1
// baseline (499.505 us; speedup 1.0000x reference)
//
#include <hip/hip_runtime.h>
#include <math.h>

// Problem constants (from reference setup_inputs): B=8, C=128, O=128, H=W=64,
// k=3, dilation=1, deformable groups=1, stride=1, pad=1. All fp32.
constexpr int Bn = 8, Cn = 128, On = 128, Hn = 64, Wn = 64;
constexpr int KK = 9;          // k*k
constexpr int PAD = 1;
constexpr int BDIM = 256;
constexpr int CCH = 4;         // channels per LDS chunk
constexpr int NCT = CCH * KK;  // 36 (c,t) pairs per chunk
constexpr int MW = KK * Wn;    // 576 meta entries per row

#define FMA4(A, S, W)                          \
    A.x = fmaf((S).x, (W), A.x);               \
    A.y = fmaf((S).y, (W), A.y);               \
    A.z = fmaf((S).z, (W), A.z);               \
    A.w = fmaf((S).w, (W), A.w);

__global__ __launch_bounds__(BDIM, 2)
void dcn_v2_kernel(const float* __restrict__ x,
                   const float* __restrict__ offs,
                   const float* __restrict__ mask,
                   const float* __restrict__ weight,
                   const float* __restrict__ bias,
                   float* __restrict__ out)
{
    // LDS: 9216 + 9216 + 9216 + 18432 = 46,080 B
    __shared__ float wmeta[4 * MW];   // corner weights (premul by mask, 0 if OOB)
    __shared__ int   imeta[4 * MW];   // clamped gather index into 64x64 plane
    __shared__ float ssh[NCT * Wn];   // sampled[c*9+t][px] for current chunk
    __shared__ float wsh[NCT * On];   // weight[c*9+t][o] for current chunk

    const int tid = threadIdx.x;
    const int b = blockIdx.x >> 6;    // blockIdx.x / H
    const int h = blockIdx.x & 63;    // blockIdx.x % H

    // ---- Stage 0: sampling metadata for this row (9 taps x 64 px) ----
    for (int e = tid; e < MW; e += BDIM) {
        const int t  = e >> 6;
        const int px = e & 63;
        const int ty = t / 3, tx = t - ty * 3;
        const float oy = offs[((b * 18 + 2 * t    ) * Hn + h) * Wn + px];
        const float ox = offs[((b * 18 + 2 * t + 1) * Hn + h) * Wn + px];
        const float m  = mask[((b * KK + t) * Hn + h) * Wn + px];
        const float py = (float)(h - PAD + ty) + oy;
        const float qx = (float)(px - PAD + tx) + ox;
        const float y0 = floorf(py), x0 = floorf(qx);
        const float wy1 = py - y0, wx1 = qx - x0;
        const float wy0 = 1.f - wy1, wx0 = 1.f - wx1;
        const float cw[4] = { wy0 * wx0, wy0 * wx1, wy1 * wx0, wy1 * wx1 };
        #pragma unroll
        for (int k = 0; k < 4; ++k) {
            const float yk = y0 + (float)(k >> 1);
            const float xk = x0 + (float)(k & 1);
            const bool valid = (yk >= 0.f) && (yk <= (float)(Hn - 1)) &&
                               (xk >= 0.f) && (xk <= (float)(Wn - 1));
            const int yc = (int)fminf(fmaxf(yk, 0.f), (float)(Hn - 1));
            const int xc = (int)fminf(fmaxf(xk, 0.f), (float)(Wn - 1));
            wmeta[k * MW + e] = valid ? cw[k] * m : 0.f;
            imeta[k * MW + e] = yc * Wn + xc;
        }
    }
    __syncthreads();

    // Register micro-tile: 4 px (contiguous) x 8 O per thread
    const int px0 = (tid & 15) << 2;   // 0,4,...,60
    const int oo  = (tid >> 4) << 3;   // 0,8,...,120

    float4 acc[8];
    #pragma unroll
    for (int j = 0; j < 8; ++j) acc[j] = make_float4(0.f, 0.f, 0.f, 0.f);

    for (int cb = 0; cb < Cn / CCH; ++cb) {
        // ---- stage weights: wsh[r][o] = weight[o*1152 + cb*36 + r], r=c*9+t ----
        #pragma unroll
        for (int it = 0; it < (NCT * On) / BDIM; ++it) {   // 18 iters
            const int e = tid + it * BDIM;
            const int r = e >> 7;        // 0..35 (wave-uniform)
            const int o = e & 127;       // consecutive lanes -> consecutive o
            wsh[r * On + o] = weight[o * (Cn * KK) + cb * NCT + r];
        }
        // ---- stage sampled values: ssh[ct][px], ct = c*9 + t ----
        #pragma unroll
        for (int it = 0; it < (NCT * Wn) / BDIM; ++it) {   // 9 iters
            const int e  = tid + it * BDIM;
            const int px = e & 63;
            const int ct = e >> 6;       // 0..35
            const int c  = ct / 9;
            const int mb = (ct - c * 9) * Wn + px;
            const float* xp = x + (((b * Cn) + cb * CCH + c) << 12);
            float v =  wmeta[mb]           * xp[imeta[mb]];
            v = fmaf(wmeta[MW     + mb], xp[imeta[MW     + mb]], v);
            v = fmaf(wmeta[2 * MW + mb], xp[imeta[2 * MW + mb]], v);
            v = fmaf(wmeta[3 * MW + mb], xp[imeta[3 * MW + mb]], v);
            ssh[ct * Wn + px] = v;
        }
        __syncthreads();

        // ---- FMA: 36 (c,t) pairs x 32 FMA per thread ----
        #pragma unroll 6
        for (int ct = 0; ct < NCT; ++ct) {
            const float4 sv = *(const float4*)&ssh[ct * Wn + px0];
            const float4 wa = *(const float4*)&wsh[ct * On + oo];
            const float4 wb = *(const float4*)&wsh[ct * On + oo + 4];
            FMA4(acc[0], sv, wa.x);
            FMA4(acc[1], sv, wa.y);
            FMA4(acc[2], sv, wa.z);
            FMA4(acc[3], sv, wa.w);
            FMA4(acc[4], sv, wb.x);
            FMA4(acc[5], sv, wb.y);
            FMA4(acc[6], sv, wb.z);
            FMA4(acc[7], sv, wb.w);
        }
        __syncthreads();
    }

    // ---- epilogue: add bias, store float4 per output channel ----
    #pragma unroll
    for (int j = 0; j < 8; ++j) {
        const float bv = bias[oo + j];
        float4 r = acc[j];
        r.x += bv; r.y += bv; r.z += bv; r.w += bv;
        *(float4*)&out[((b * On + oo + j) * Hn + h) * Wn + px0] = r;
    }
}

extern "C" void kernel_launch(void* const* d_in, const int* in_sizes, int n_in,
                              void* d_out, int out_size, void* d_ws, size_t ws_size,
                              hipStream_t stream) {
    const float* x      = (const float*)d_in[0];
    const float* offs   = (const float*)d_in[1];
    const float* mask   = (const float*)d_in[2];
    const float* weight = (const float*)d_in[3];
    const float* bias   = (const float*)d_in[4];
    float* out = (float*)d_out;

    dcn_v2_kernel<<<dim3(Bn * Hn), dim3(BDIM), 0, stream>>>(
        x, offs, mask, weight, bias, out);
}

// Round 2
// 469.549 us; speedup vs baseline: 1.0638x; 1.0638x over previous
//
#include <hip/hip_runtime.h>
#include <math.h>

// DCN v2: B=8, C=128, O=128, H=W=64, k=3, dil=1, dg=1, stride=1, pad=1. fp32.
constexpr int Bn = 8, Cn = 128, On = 128, Hn = 64, Wn = 64;
constexpr int KK = 9;
constexpr int PAD = 1;
constexpr int BDIM = 256;
constexpr int PXB = 32;          // pixels per block (half row)
constexpr int CCH = 4;           // channels per LDS chunk
constexpr int NCT = CCH * KK;    // 36
constexpr int MW = KK * PXB;     // 288 meta entries per block

#define FMA4(A, S, W)                          \
    A.x = fmaf((S).x, (W), A.x);               \
    A.y = fmaf((S).y, (W), A.y);               \
    A.z = fmaf((S).z, (W), A.z);               \
    A.w = fmaf((S).w, (W), A.w);

__global__ __launch_bounds__(BDIM, 4)
void dcn_v2_kernel(const float* __restrict__ x,
                   const float* __restrict__ offs,
                   const float* __restrict__ mask,
                   const float* __restrict__ weight,
                   const float* __restrict__ bias,
                   float* __restrict__ out)
{
    // LDS: 4608 + 4608 + 4608 + 18432 = 32,256 B -> 4 blocks/CU
    __shared__ float wmeta[4 * MW];   // corner weights (premul mask, 0 if OOB)
    __shared__ int   imeta[4 * MW];   // clamped gather index into 64x64 plane
    __shared__ float ssh[NCT * PXB];  // sampled[c*9+t][px] current chunk
    __shared__ float wsh[NCT * On];   // weight[c*9+t][o] current chunk

    const int tid    = threadIdx.x;
    const int b      = blockIdx.x >> 7;         // / (H*2)
    const int h      = (blockIdx.x >> 1) & 63;
    const int pxbase = (blockIdx.x & 1) * PXB;  // half-row offset

    // ---- Stage 0: sampling metadata (9 taps x 32 px) ----
    for (int e = tid; e < MW; e += BDIM) {
        const int t  = e >> 5;          // tap 0..8
        const int px = e & 31;          // local px
        const int pg = pxbase + px;     // global px
        const int ty = t / 3, tx = t - ty * 3;
        const float oy = offs[((b * 18 + 2 * t    ) * Hn + h) * Wn + pg];
        const float ox = offs[((b * 18 + 2 * t + 1) * Hn + h) * Wn + pg];
        const float m  = mask[((b * KK + t) * Hn + h) * Wn + pg];
        const float py = (float)(h - PAD + ty) + oy;
        const float qx = (float)(pg - PAD + tx) + ox;
        const float y0 = floorf(py), x0 = floorf(qx);
        const float wy1 = py - y0, wx1 = qx - x0;
        const float wy0 = 1.f - wy1, wx0 = 1.f - wx1;
        const float cw[4] = { wy0 * wx0, wy0 * wx1, wy1 * wx0, wy1 * wx1 };
        #pragma unroll
        for (int k = 0; k < 4; ++k) {
            const float yk = y0 + (float)(k >> 1);
            const float xk = x0 + (float)(k & 1);
            const bool valid = (yk >= 0.f) && (yk <= (float)(Hn - 1)) &&
                               (xk >= 0.f) && (xk <= (float)(Wn - 1));
            const int yc = (int)fminf(fmaxf(yk, 0.f), (float)(Hn - 1));
            const int xc = (int)fminf(fmaxf(xk, 0.f), (float)(Wn - 1));
            wmeta[k * MW + e] = valid ? cw[k] * m : 0.f;
            imeta[k * MW + e] = yc * Wn + xc;
        }
    }
    __syncthreads();

    // Register micro-tile: 4 px x 4 O per thread
    const int px0 = (tid & 7) << 2;    // 0..28
    const int oo  = (tid >> 3) << 2;   // 0..124

    float4 acc[4];
    #pragma unroll
    for (int j = 0; j < 4; ++j) acc[j] = make_float4(0.f, 0.f, 0.f, 0.f);

    for (int cb = 0; cb < Cn / CCH; ++cb) {
        // ---- stage weights: wsh[r][o], r = c*9+t (matches weight [C][9] inner) ----
        #pragma unroll
        for (int it = 0; it < (NCT * On) / BDIM; ++it) {   // 18 iters
            const int e = tid + it * BDIM;
            const int r = e >> 7;        // wave-uniform
            const int o = e & 127;       // consecutive lanes -> consecutive o
            wsh[r * On + o] = weight[o * (Cn * KK) + cb * NCT + r];
        }
        // ---- stage sampled values: ssh[ct][px] ----
        for (int e = tid; e < NCT * PXB; e += BDIM) {       // 4.5 iters
            const int px = e & 31;
            const int ct = e >> 5;       // 0..35 = c*9+t
            const int c  = ct / 9;
            const int mb = (ct - c * 9) * PXB + px;
            const float* xp = x + (((b * Cn) + cb * CCH + c) << 12);
            float v =  wmeta[mb]           * xp[imeta[mb]];
            v = fmaf(wmeta[MW     + mb], xp[imeta[MW     + mb]], v);
            v = fmaf(wmeta[2 * MW + mb], xp[imeta[2 * MW + mb]], v);
            v = fmaf(wmeta[3 * MW + mb], xp[imeta[3 * MW + mb]], v);
            ssh[ct * PXB + px] = v;
        }
        __syncthreads();

        // ---- FMA: 36 (c,t) pairs x 16 FMA per thread ----
        #pragma unroll 6
        for (int ct = 0; ct < NCT; ++ct) {
            const float4 sv = *(const float4*)&ssh[ct * PXB + px0];
            const float4 wa = *(const float4*)&wsh[ct * On + oo];
            FMA4(acc[0], sv, wa.x);
            FMA4(acc[1], sv, wa.y);
            FMA4(acc[2], sv, wa.z);
            FMA4(acc[3], sv, wa.w);
        }
        __syncthreads();
    }

    // ---- epilogue ----
    #pragma unroll
    for (int j = 0; j < 4; ++j) {
        const float bv = bias[oo + j];
        float4 r = acc[j];
        r.x += bv; r.y += bv; r.z += bv; r.w += bv;
        *(float4*)&out[((b * On + oo + j) * Hn + h) * Wn + pxbase + px0] = r;
    }
}

extern "C" void kernel_launch(void* const* d_in, const int* in_sizes, int n_in,
                              void* d_out, int out_size, void* d_ws, size_t ws_size,
                              hipStream_t stream) {
    const float* x      = (const float*)d_in[0];
    const float* offs   = (const float*)d_in[1];
    const float* mask   = (const float*)d_in[2];
    const float* weight = (const float*)d_in[3];
    const float* bias   = (const float*)d_in[4];
    float* out = (float*)d_out;

    dcn_v2_kernel<<<dim3(Bn * Hn * 2), dim3(BDIM), 0, stream>>>(
        x, offs, mask, weight, bias, out);
}

// Round 3
// 372.438 us; speedup vs baseline: 1.3412x; 1.2607x over previous
//
#include <hip/hip_runtime.h>
#include <math.h>

// DCN v2: B=8, C=128, O=128, H=W=64, k=3, dil=1, dg=1, stride=1, pad=1. fp32.
constexpr int Bn = 8, Cn = 128, On = 128, Hn = 64, Wn = 64;
constexpr int KK = 9, PAD = 1, BDIM = 256;
constexpr int PXB = 32;           // pixels per block (half row)
constexpr int CCH = 4;            // channels per chunk
constexpr int NCT = CCH * KK;     // 36 k-slices per chunk
constexpr int MW  = KK * PXB;     // 288 meta entries
constexpr int NCHUNK = Cn / CCH;  // 32
constexpr int SSE = NCT * PXB;    // 1152 ssh elements (4.5 per thread)
constexpr int KTOT = Cn * KK;     // 1152

#define FMA4(A, S, W)                          \
    A.x = fmaf((S).x, (W), A.x);               \
    A.y = fmaf((S).y, (W), A.y);               \
    A.z = fmaf((S).z, (W), A.z);               \
    A.w = fmaf((S).w, (W), A.w);

// weight [O][C*9] -> wT [C*9][O] so per-chunk staging is coalesced float4
__global__ void transpose_w_kernel(const float* __restrict__ w,
                                   float* __restrict__ wT) {
    const int e = blockIdx.x * BDIM + threadIdx.x;   // < 147456
    const int o = e & 127;
    const int r = e >> 7;
    wT[r * On + o] = w[o * KTOT + r];
}

template <bool TRANS>
__global__ __launch_bounds__(BDIM, 4)
void dcn_v2_kernel(const float* __restrict__ x,
                   const float* __restrict__ offs,
                   const float* __restrict__ mask,
                   const float* __restrict__ wsrc,   // wT if TRANS else weight
                   const float* __restrict__ bias,
                   float* __restrict__ out)
{
    // LDS: 4608 + 4608 + 4608 + 18432 = 32,256 B -> 4 blocks/CU
    __shared__ float wmeta[4 * MW];
    __shared__ int   imeta[4 * MW];
    __shared__ float ssh[SSE];
    __shared__ float wsh[NCT * On];

    const int tid = threadIdx.x;
    // b == blockIdx.x % 8: with round-robin block->XCD dispatch, each batch's
    // blocks land on one XCD -> x[b] (2MB) + weight (0.58MB) fit its 4MB L2.
    const int b      = blockIdx.x & 7;
    const int rem    = blockIdx.x >> 3;
    const int h      = rem >> 1;
    const int pxbase = (rem & 1) * PXB;

    // ---- Stage 0: sampling metadata (9 taps x 32 px) ----
    for (int e = tid; e < MW; e += BDIM) {
        const int t  = e >> 5;
        const int px = e & 31;
        const int pg = pxbase + px;
        const int ty = t / 3, tx = t - ty * 3;
        const float oy = offs[((b * 18 + 2 * t    ) * Hn + h) * Wn + pg];
        const float ox = offs[((b * 18 + 2 * t + 1) * Hn + h) * Wn + pg];
        const float m  = mask[((b * KK + t) * Hn + h) * Wn + pg];
        const float py = (float)(h - PAD + ty) + oy;
        const float qx = (float)(pg - PAD + tx) + ox;
        const float y0 = floorf(py), x0 = floorf(qx);
        const float wy1 = py - y0, wx1 = qx - x0;
        const float wy0 = 1.f - wy1, wx0 = 1.f - wx1;
        const float cw[4] = { wy0 * wx0, wy0 * wx1, wy1 * wx0, wy1 * wx1 };
        #pragma unroll
        for (int k = 0; k < 4; ++k) {
            const float yk = y0 + (float)(k >> 1);
            const float xk = x0 + (float)(k & 1);
            const bool valid = (yk >= 0.f) && (yk <= (float)(Hn - 1)) &&
                               (xk >= 0.f) && (xk <= (float)(Wn - 1));
            const int yc = (int)fminf(fmaxf(yk, 0.f), (float)(Hn - 1));
            const int xc = (int)fminf(fmaxf(xk, 0.f), (float)(Wn - 1));
            wmeta[k * MW + e] = valid ? cw[k] * m : 0.f;
            imeta[k * MW + e] = yc * Wn + xc;
        }
    }
    __syncthreads();

    // ---- per-thread cb-invariant gather constants ----
    // ssh element e_it = tid + it*256; threads <128 own 5 elements, rest 4.
    const int nE = (tid < SSE - 4 * BDIM) ? 5 : 4;   // wave-uniform
    int gofs[5][4];   // (c<<12) + plane index, per corner
    #pragma unroll
    for (int it = 0; it < 5; ++it) {
        if (it < nE) {
            const int e  = tid + it * BDIM;
            const int ct = e >> 5;
            const int c  = ct / 9;
            const int mb = (ct - c * 9) * PXB + (e & 31);
            #pragma unroll
            for (int k = 0; k < 4; ++k)
                gofs[it][k] = (c << 12) + imeta[k * MW + mb];
        }
    }

    const float* xb = x + (((size_t)b * Cn) << 12);
    const int px0 = (tid & 7) << 2;
    const int oo  = (tid >> 3) << 2;

    float  gv[5][4];    // prefetched gathered x values
    float4 wv4[5];      // prefetched weights (TRANS path)
    float  wvs[18];     // prefetched weights (fallback path)

    float4 acc[4];
    #pragma unroll
    for (int j = 0; j < 4; ++j) acc[j] = make_float4(0.f, 0.f, 0.f, 0.f);

    // ---- prologue: prefetch chunk 0 ----
    {
        const float* xc = xb;
        #pragma unroll
        for (int it = 0; it < 5; ++it)
            if (it < nE) {
                #pragma unroll
                for (int k = 0; k < 4; ++k) gv[it][k] = xc[gofs[it][k]];
            }
        if (TRANS) {
            const float4* wt4 = (const float4*)wsrc;
            #pragma unroll
            for (int it = 0; it < 5; ++it)
                if (it < nE) wv4[it] = wt4[tid + it * BDIM];
        } else {
            #pragma unroll
            for (int it = 0; it < 18; ++it) {
                const int e = tid + it * BDIM;
                wvs[it] = wsrc[(e & 127) * KTOT + (e >> 7)];
            }
        }
    }

    for (int cb = 0; cb < NCHUNK; ++cb) {
        // ---- store phase: prefetched regs -> LDS ----
        #pragma unroll
        for (int it = 0; it < 5; ++it)
            if (it < nE) {
                const int e  = tid + it * BDIM;
                const int ct = e >> 5;
                const int c  = ct / 9;
                const int mb = (ct - c * 9) * PXB + (e & 31);
                float v =       wmeta[mb]          * gv[it][0];
                v = fmaf(wmeta[MW     + mb], gv[it][1], v);
                v = fmaf(wmeta[2 * MW + mb], gv[it][2], v);
                v = fmaf(wmeta[3 * MW + mb], gv[it][3], v);
                ssh[e] = v;
            }
        if (TRANS) {
            float4* w4 = (float4*)wsh;
            #pragma unroll
            for (int it = 0; it < 5; ++it)
                if (it < nE) w4[tid + it * BDIM] = wv4[it];
        } else {
            #pragma unroll
            for (int it = 0; it < 18; ++it)
                wsh[tid + it * BDIM] = wvs[it];
        }
        __syncthreads();

        // ---- issue next chunk's loads; latency hidden by FMA phase below ----
        if (cb + 1 < NCHUNK) {
            const float* xc = xb + ((cb + 1) << 14);
            #pragma unroll
            for (int it = 0; it < 5; ++it)
                if (it < nE) {
                    #pragma unroll
                    for (int k = 0; k < 4; ++k) gv[it][k] = xc[gofs[it][k]];
                }
            if (TRANS) {
                const float4* wt4 =
                    (const float4*)(wsrc + (size_t)(cb + 1) * (NCT * On));
                #pragma unroll
                for (int it = 0; it < 5; ++it)
                    if (it < nE) wv4[it] = wt4[tid + it * BDIM];
            } else {
                #pragma unroll
                for (int it = 0; it < 18; ++it) {
                    const int e = tid + it * BDIM;
                    wvs[it] = wsrc[(e & 127) * KTOT + (cb + 1) * NCT + (e >> 7)];
                }
            }
        }

        // ---- FMA: 36 k-slices x 16 FMA per thread ----
        #pragma unroll 6
        for (int ct = 0; ct < NCT; ++ct) {
            const float4 sv = *(const float4*)&ssh[ct * PXB + px0];
            const float4 wa = *(const float4*)&wsh[ct * On + oo];
            FMA4(acc[0], sv, wa.x);
            FMA4(acc[1], sv, wa.y);
            FMA4(acc[2], sv, wa.z);
            FMA4(acc[3], sv, wa.w);
        }
        __syncthreads();
    }

    // ---- epilogue ----
    #pragma unroll
    for (int j = 0; j < 4; ++j) {
        const float bv = bias[oo + j];
        float4 r = acc[j];
        r.x += bv; r.y += bv; r.z += bv; r.w += bv;
        *(float4*)&out[((b * On + oo + j) * Hn + h) * Wn + pxbase + px0] = r;
    }
}

extern "C" void kernel_launch(void* const* d_in, const int* in_sizes, int n_in,
                              void* d_out, int out_size, void* d_ws, size_t ws_size,
                              hipStream_t stream) {
    const float* x      = (const float*)d_in[0];
    const float* offs   = (const float*)d_in[1];
    const float* mask   = (const float*)d_in[2];
    const float* weight = (const float*)d_in[3];
    const float* bias   = (const float*)d_in[4];
    float* out = (float*)d_out;

    const size_t wt_bytes = (size_t)KTOT * On * sizeof(float);
    if (ws_size >= wt_bytes) {
        float* wT = (float*)d_ws;
        transpose_w_kernel<<<dim3(KTOT * On / BDIM), dim3(BDIM), 0, stream>>>(
            weight, wT);
        dcn_v2_kernel<true><<<dim3(Bn * Hn * 2), dim3(BDIM), 0, stream>>>(
            x, offs, mask, wT, bias, out);
    } else {
        dcn_v2_kernel<false><<<dim3(Bn * Hn * 2), dim3(BDIM), 0, stream>>>(
            x, offs, mask, weight, bias, out);
    }
}

// Round 6
// 157.502 us; speedup vs baseline: 3.1714x; 2.3647x over previous
//
#include <hip/hip_runtime.h>
#include <math.h>

// DCN v2: B=8, C=128, O=128, H=W=64, k=3, dil=1, dg=1, stride=1, pad=1.
// MFMA path: per (b,h) block -- bilinear gathers served from a 10-row LDS band
// (out-of-band waves fall back to clamped GLOBAL reads for all 4 corners);
// GEMM over K=C*9 via verified mfma_f32_16x16x32_bf16 (M=o, N=px).
// d_ws use (bf16 weight repack) is GUARDED by ws_size; fallback = proven R2 kernel.
constexpr int Bn = 8, Cn = 128, On = 128, Hn = 64, Wn = 64;
constexpr int KK = 9, PAD = 1, BDIM = 256;
constexpr int CG = 16;               // channels per granule
constexpr int NG = Cn / CG;          // 8 granules
constexpr int KG = 160;              // k'/granule: 144 real (tap-major 16ch) + 16 zero
constexpr int KTOT = NG * KG;        // 1280 padded K
constexpr int BANDH = 10;            // band rows
constexpr int XST = 656;             // band ch stride (floats): 8 lead pad + 640 + 8 tail
constexpr int AST = 168;             // ash k-stride (bf16): 160 + 8 pad
constexpr int ME = KK * Wn;          // 576 (tap,px) meta elements

typedef __attribute__((ext_vector_type(8))) short bf16x8;
typedef __attribute__((ext_vector_type(4))) float f32x4;
typedef unsigned short u16;
typedef unsigned int u32;

__device__ inline u16 f2bf(float f) {
    union { float f; u32 u; } v; v.f = f;
    return (u16)((v.u + 0x7FFFu + ((v.u >> 16) & 1u)) >> 16);
}

// weight [O][C*9] fp32 -> wbf [O][KTOT] bf16, k' = g*KG + t*16 + cl
__global__ void wprep_kernel(const float* __restrict__ w, u16* __restrict__ wbf) {
    const int e = blockIdx.x * BDIM + threadIdx.x;    // < 163840
    const int o  = e / KTOT;
    const int kp = e - o * KTOT;
    const int g  = kp / KG;
    const int r  = kp - g * KG;
    const int t  = r >> 4;
    const int cl = r & 15;
    float v = 0.f;
    if (t < KK) v = w[o * (Cn * KK) + (g * CG + cl) * KK + t];
    wbf[e] = f2bf(v);
}

__global__ __launch_bounds__(BDIM, 2)
void dcn_mfma_kernel(const float* __restrict__ x,
                     const float* __restrict__ offs,
                     const float* __restrict__ mask,
                     const u16*   __restrict__ wbf,
                     const float* __restrict__ bias,
                     float* __restrict__ out)
{
    __shared__ float xband[CG * XST];   // 41,984 B
    __shared__ u16   ash[Wn * AST];     // 21,504 B  (total 63,488 -> 2 blk/CU)

    const int tid = threadIdx.x;
    const int b   = blockIdx.x & 7;     // batch<->XCD affinity
    const int h   = blockIdx.x >> 3;
    const int r0  = min(max(h - 4, 0), Hn - BANDH);

    const int cl16 = tid >> 4, l16b = tid & 15;
    float4 bnd[BANDH];
    {   // issue band-0 loads early (hidden under meta VALU)
        const float* xp = x + (((size_t)(b * Cn + cl16)) << 12) + r0 * Wn + (l16b << 2);
        #pragma unroll
        for (int r = 0; r < BANDH; ++r) bnd[r] = *(const float4*)(xp + r * Wn);
    }

    // ---- meta in REGISTERS: corner weights mw, coord code mq, LDS index mi ----
    // code qv = (yr<<8)|(x0+1); stored ~qv (negative) if row outside band.
    float4 mw[3]; int2 mq[3]; int2 mi[3];
    #pragma unroll
    for (int it = 0; it < 3; ++it) {
        mw[it] = make_float4(0.f, 0.f, 0.f, 0.f);
        mq[it] = make_int2(r0 << 8, r0 << 8);
        mi[it] = make_int2(7, 7);
        const int e = tid + it * BDIM;
        if (e < ME) {
            const int t = e >> 6, px = e & 63;
            const int ty = t / 3, tx = t - ty * 3;
            const float oy = offs[((b * 18 + 2 * t    ) * Hn + h) * Wn + px];
            const float ox = offs[((b * 18 + 2 * t + 1) * Hn + h) * Wn + px];
            const float m  = mask[((b * KK + t) * Hn + h) * Wn + px];
            const float py = (float)(h - PAD + ty) + oy;
            const float qx = (float)(px - PAD + tx) + ox;
            const float fy = floorf(py), fx = floorf(qx);
            const float wy1 = py - fy, wx1 = qx - fx;
            const float wy0 = 1.f - wy1, wx0 = 1.f - wx1;
            const int y0 = (int)fy, x0 = (int)fx;
            const bool cx0 = (x0 >= 0) && (x0 < Wn);
            const bool cx1 = (x0 >= -1) && (x0 < Wn - 1);
            const float wr[2] = { wy0, wy1 };
            float wout[4]; int qout[2], iout[2];
            #pragma unroll
            for (int j = 0; j < 2; ++j) {
                const int yr = y0 + j;
                const bool rv = (yr >= 0) && (yr < Hn);
                wout[2 * j]     = (rv && cx0) ? wr[j] * wx0 * m : 0.f;
                wout[2 * j + 1] = (rv && cx1) ? wr[j] * wx1 * m : 0.f;
                int qv;
                if (!rv || (!cx0 && !cx1)) qv = r0 << 8;          // junk: w=0, reads pad
                else                       qv = (yr << 8) | (x0 + 1);
                const bool inband = (qv >> 8) >= r0 && (qv >> 8) < r0 + BANDH;
                qout[j] = inband ? qv : ~qv;
                iout[j] = (((qv >> 8) - r0) << 6) + (qv & 255) + 7; // junk->7 (pad)
            }
            mw[it] = make_float4(wout[0], wout[1], wout[2], wout[3]);
            mq[it] = make_int2(qout[0], qout[1]);
            mi[it] = make_int2(iout[0], iout[1]);
        }
    }

    // ---- store band 0; zero band pads; zero ash k=144..159 ----
    {
        float* dp = &xband[cl16 * XST + 8 + (l16b << 2)];
        #pragma unroll
        for (int r = 0; r < BANDH; ++r) *(float4*)(dp + r * 64) = bnd[r];
        const int padi = (l16b < 8) ? l16b : (640 + l16b);  // 0..7, 648..655
        xband[cl16 * XST + padi] = 0.f;
        const int px = tid & 63, kz = 144 + ((tid >> 6) << 2);
        u16* d = &ash[px * AST + kz];
        d[0] = 0; d[1] = 0; d[2] = 0; d[3] = 0;
    }
    __syncthreads();

    const int wv = tid >> 6, ln = tid & 63, quad = ln >> 4, l16 = ln & 15;
    const u16* wrow0 = wbf + (size_t)(wv * 32 + l16) * KTOT;

    f32x4 acc[2][4];
    #pragma unroll
    for (int mt = 0; mt < 2; ++mt)
        #pragma unroll
        for (int nt = 0; nt < 4; ++nt) acc[mt][nt] = (f32x4){0.f, 0.f, 0.f, 0.f};

    for (int g = 0; g < NG; ++g) {
        // ---- sampling: band + meta -> ash (bf16) ----
        #pragma unroll
        for (int it = 0; it < 3; ++it) {
            const int e = tid + it * BDIM;
            if (e < ME) {
                const int t = e >> 6, px = e & 63;
                const float4 w  = mw[it];
                const int2   q  = mq[it];
                const int2   ix = mi[it];
                u16 av[CG];
                if (!__any((q.x | q.y) < 0)) {     // all corners in band: LDS path
                    #pragma unroll
                    for (int cl = 0; cl < CG; ++cl) {
                        const float* xc = &xband[cl * XST];
                        const float t0 = xc[ix.x], t1 = xc[ix.x + 1];
                        const float b0 = xc[ix.y], b1 = xc[ix.y + 1];
                        av[cl] = f2bf(fmaf(w.x, t0, fmaf(w.y, t1,
                                      fmaf(w.z, b0, w.w * b1))));
                    }
                } else {                            // rare: clamped global reads
                    const int qx = q.x < 0 ? ~q.x : q.x;
                    const int qy = q.y < 0 ? ~q.y : q.y;
                    const int yrx = qx >> 8, yry = qy >> 8;
                    const int xx = (qx & 255) - 1, xy = (qy & 255) - 1;
                    const int ax0 = max(xx, 0), ax1 = min(xx + 1, Wn - 1);
                    const int ay0 = max(xy, 0), ay1 = min(xy + 1, Wn - 1);
                    const float* gp = x + (((size_t)(b * Cn + g * CG)) << 12);
                    for (int cl = 0; cl < CG; ++cl) {
                        const float* gc = gp + (cl << 12);
                        const float t0 = gc[yrx * Wn + ax0], t1 = gc[yrx * Wn + ax1];
                        const float b0 = gc[yry * Wn + ay0], b1 = gc[yry * Wn + ay1];
                        av[cl] = f2bf(fmaf(w.x, t0, fmaf(w.y, t1,
                                      fmaf(w.z, b0, w.w * b1))));
                    }
                }
                u32 pk[8];
                #pragma unroll
                for (int q2 = 0; q2 < 8; ++q2)
                    pk[q2] = (u32)av[2 * q2] | ((u32)av[2 * q2 + 1] << 16);
                u32* d = (u32*)&ash[px * AST + (t << 4)];
                *(uint4*)d       = make_uint4(pk[0], pk[1], pk[2], pk[3]);
                *(uint4*)(d + 4) = make_uint4(pk[4], pk[5], pk[6], pk[7]);
            }
        }
        __syncthreads();

        // ---- issue next band's global loads (drain during MFMA) ----
        if (g + 1 < NG) {
            const float* xp = x + (((size_t)(b * Cn + (g + 1) * CG + cl16)) << 12)
                              + r0 * Wn + (l16b << 2);
            #pragma unroll
            for (int r = 0; r < BANDH; ++r) bnd[r] = *(const float4*)(xp + r * Wn);
        }

        // ---- MFMA: 5 K-steps of 32 ----
        #pragma unroll
        for (int s = 0; s < 5; ++s) {
            const int kg = g * KG + s * 32 + quad * 8;
            const int kl = s * 32 + quad * 8;
            const bf16x8 a0 = *(const bf16x8*)(wrow0 + kg);
            const bf16x8 a1 = *(const bf16x8*)(wrow0 + 16 * KTOT + kg);
            const bf16x8 b0 = *(const bf16x8*)&ash[(0 * 16 + l16) * AST + kl];
            const bf16x8 b1 = *(const bf16x8*)&ash[(1 * 16 + l16) * AST + kl];
            const bf16x8 b2 = *(const bf16x8*)&ash[(2 * 16 + l16) * AST + kl];
            const bf16x8 b3 = *(const bf16x8*)&ash[(3 * 16 + l16) * AST + kl];
            acc[0][0] = __builtin_amdgcn_mfma_f32_16x16x32_bf16(a0, b0, acc[0][0], 0, 0, 0);
            acc[0][1] = __builtin_amdgcn_mfma_f32_16x16x32_bf16(a0, b1, acc[0][1], 0, 0, 0);
            acc[0][2] = __builtin_amdgcn_mfma_f32_16x16x32_bf16(a0, b2, acc[0][2], 0, 0, 0);
            acc[0][3] = __builtin_amdgcn_mfma_f32_16x16x32_bf16(a0, b3, acc[0][3], 0, 0, 0);
            acc[1][0] = __builtin_amdgcn_mfma_f32_16x16x32_bf16(a1, b0, acc[1][0], 0, 0, 0);
            acc[1][1] = __builtin_amdgcn_mfma_f32_16x16x32_bf16(a1, b1, acc[1][1], 0, 0, 0);
            acc[1][2] = __builtin_amdgcn_mfma_f32_16x16x32_bf16(a1, b2, acc[1][2], 0, 0, 0);
            acc[1][3] = __builtin_amdgcn_mfma_f32_16x16x32_bf16(a1, b3, acc[1][3], 0, 0, 0);
        }

        // ---- write next band to LDS ----
        if (g + 1 < NG) {
            float* dp = &xband[cl16 * XST + 8 + (l16b << 2)];
            #pragma unroll
            for (int r = 0; r < BANDH; ++r) *(float4*)(dp + r * 64) = bnd[r];
        }
        __syncthreads();
    }

    // ---- epilogue: D[m=o][n=px], col=lane&15 -> coalesced px stores ----
    float* ob = out + (((size_t)b * On) * Hn + h) * Wn;
    #pragma unroll
    for (int mt = 0; mt < 2; ++mt)
        #pragma unroll
        for (int nt = 0; nt < 4; ++nt)
            #pragma unroll
            for (int r = 0; r < 4; ++r) {
                const int o  = wv * 32 + mt * 16 + quad * 4 + r;
                const int px = nt * 16 + l16;
                ob[(size_t)o * (Hn * Wn) + px] = acc[mt][nt][r] + bias[o];
            }
}

// ================= fallback: proven R2 fp32 kernel (no d_ws) =================
constexpr int FB_PXB = 32, FB_CCH = 4, FB_NCT = FB_CCH * KK, FB_MW = KK * FB_PXB;

#define FMA4(A, S, W)                          \
    A.x = fmaf((S).x, (W), A.x);               \
    A.y = fmaf((S).y, (W), A.y);               \
    A.z = fmaf((S).z, (W), A.z);               \
    A.w = fmaf((S).w, (W), A.w);

__global__ __launch_bounds__(BDIM, 4)
void dcn_fb_kernel(const float* __restrict__ x,
                   const float* __restrict__ offs,
                   const float* __restrict__ mask,
                   const float* __restrict__ weight,
                   const float* __restrict__ bias,
                   float* __restrict__ out)
{
    __shared__ float wmeta[4 * FB_MW];
    __shared__ int   imeta[4 * FB_MW];
    __shared__ float ssh[FB_NCT * FB_PXB];
    __shared__ float wsh[FB_NCT * On];

    const int tid    = threadIdx.x;
    const int b      = blockIdx.x & 7;
    const int rem    = blockIdx.x >> 3;
    const int h      = rem >> 1;
    const int pxbase = (rem & 1) * FB_PXB;

    for (int e = tid; e < FB_MW; e += BDIM) {
        const int t  = e >> 5;
        const int px = e & 31;
        const int pg = pxbase + px;
        const int ty = t / 3, tx = t - ty * 3;
        const float oy = offs[((b * 18 + 2 * t    ) * Hn + h) * Wn + pg];
        const float ox = offs[((b * 18 + 2 * t + 1) * Hn + h) * Wn + pg];
        const float m  = mask[((b * KK + t) * Hn + h) * Wn + pg];
        const float py = (float)(h - PAD + ty) + oy;
        const float qx = (float)(pg - PAD + tx) + ox;
        const float y0 = floorf(py), x0 = floorf(qx);
        const float wy1 = py - y0, wx1 = qx - x0;
        const float wy0 = 1.f - wy1, wx0 = 1.f - wx1;
        const float cw[4] = { wy0 * wx0, wy0 * wx1, wy1 * wx0, wy1 * wx1 };
        #pragma unroll
        for (int k = 0; k < 4; ++k) {
            const float yk = y0 + (float)(k >> 1);
            const float xk = x0 + (float)(k & 1);
            const bool valid = (yk >= 0.f) && (yk <= (float)(Hn - 1)) &&
                               (xk >= 0.f) && (xk <= (float)(Wn - 1));
            const int yc = (int)fminf(fmaxf(yk, 0.f), (float)(Hn - 1));
            const int xc = (int)fminf(fmaxf(xk, 0.f), (float)(Wn - 1));
            wmeta[k * FB_MW + e] = valid ? cw[k] * m : 0.f;
            imeta[k * FB_MW + e] = yc * Wn + xc;
        }
    }
    __syncthreads();

    const int px0 = (tid & 7) << 2;
    const int oo  = (tid >> 3) << 2;

    float4 acc[4];
    #pragma unroll
    for (int j = 0; j < 4; ++j) acc[j] = make_float4(0.f, 0.f, 0.f, 0.f);

    for (int cb = 0; cb < Cn / FB_CCH; ++cb) {
        #pragma unroll
        for (int it = 0; it < (FB_NCT * On) / BDIM; ++it) {
            const int e = tid + it * BDIM;
            const int r = e >> 7;
            const int o = e & 127;
            wsh[r * On + o] = weight[o * (Cn * KK) + cb * FB_NCT + r];
        }
        for (int e = tid; e < FB_NCT * FB_PXB; e += BDIM) {
            const int px = e & 31;
            const int ct = e >> 5;
            const int c  = ct / 9;
            const int mb = (ct - c * 9) * FB_PXB + px;
            const float* xp = x + (((b * Cn) + cb * FB_CCH + c) << 12);
            float v =  wmeta[mb]              * xp[imeta[mb]];
            v = fmaf(wmeta[FB_MW     + mb], xp[imeta[FB_MW     + mb]], v);
            v = fmaf(wmeta[2 * FB_MW + mb], xp[imeta[2 * FB_MW + mb]], v);
            v = fmaf(wmeta[3 * FB_MW + mb], xp[imeta[3 * FB_MW + mb]], v);
            ssh[ct * FB_PXB + px] = v;
        }
        __syncthreads();

        #pragma unroll 6
        for (int ct = 0; ct < FB_NCT; ++ct) {
            const float4 sv = *(const float4*)&ssh[ct * FB_PXB + px0];
            const float4 wa = *(const float4*)&wsh[ct * On + oo];
            FMA4(acc[0], sv, wa.x);
            FMA4(acc[1], sv, wa.y);
            FMA4(acc[2], sv, wa.z);
            FMA4(acc[3], sv, wa.w);
        }
        __syncthreads();
    }

    #pragma unroll
    for (int j = 0; j < 4; ++j) {
        const float bv = bias[oo + j];
        float4 r = acc[j];
        r.x += bv; r.y += bv; r.z += bv; r.w += bv;
        *(float4*)&out[((b * On + oo + j) * Hn + h) * Wn + pxbase + px0] = r;
    }
}

extern "C" void kernel_launch(void* const* d_in, const int* in_sizes, int n_in,
                              void* d_out, int out_size, void* d_ws, size_t ws_size,
                              hipStream_t stream) {
    const float* x      = (const float*)d_in[0];
    const float* offs   = (const float*)d_in[1];
    const float* mask   = (const float*)d_in[2];
    const float* weight = (const float*)d_in[3];
    const float* bias   = (const float*)d_in[4];
    float* out = (float*)d_out;

    const size_t need = (size_t)On * KTOT * sizeof(u16);   // 327,680 B
    if (d_ws != nullptr && ws_size >= need) {
        u16* wbf = (u16*)d_ws;
        wprep_kernel<<<dim3(On * KTOT / BDIM), dim3(BDIM), 0, stream>>>(weight, wbf);
        dcn_mfma_kernel<<<dim3(Bn * Hn), dim3(BDIM), 0, stream>>>(
            x, offs, mask, wbf, bias, out);
    } else {
        dcn_fb_kernel<<<dim3(Bn * Hn * 2), dim3(BDIM), 0, stream>>>(
            x, offs, mask, weight, bias, out);
    }
}

// Round 8
// 149.463 us; speedup vs baseline: 3.3420x; 1.0538x over previous
//
#include <hip/hip_runtime.h>
#include <math.h>

// DCN v2: B=8, C=128, O=128, H=W=64, k=3, dil=1, dg=1, stride=1, pad=1.
// R8 == R7 design, de-risked: no hip_bf16.h dependency (manual RNE bf16
// packing only), __align__(16) LDS. Half-row blocks (grid 1024, 4 blk/CU),
// channel-paired bf16 LDS band, odd-dword conflict-free strides, LDS-transpose
// coalesced epilogue, GEMM via verified mfma_f32_16x16x32_bf16.
constexpr int Bn = 8, Cn = 128, On = 128, Hn = 64, Wn = 64;
constexpr int KK = 9, PAD = 1, BDIM = 256;
constexpr int PXB = 32;              // pixels per block (half row)
constexpr int CG = 16;               // channels per granule
constexpr int NG = Cn / CG;          // 8
constexpr int KG = 160;              // 144 real k-slices + 16 zero pad
constexpr int KTOT = NG * KG;        // 1280
constexpr int BANDH = 10;            // band rows
constexpr int XSTP = 657;            // pband pair stride (u32): odd -> <=2-way
constexpr int AST = 170;             // ash k-stride (u16): 85 dwords, odd
constexpr int ME = KK * PXB;         // 288 (tap,px) elements per block

typedef __attribute__((ext_vector_type(8))) short bf16x8;
typedef __attribute__((ext_vector_type(4))) float f32x4;
typedef unsigned short u16;
typedef unsigned int u32;

__device__ inline u16 f2bf(float f) {   // RNE f32->bf16 (proven in R6)
    union { float f; u32 u; } v; v.f = f;
    return (u16)((v.u + 0x7FFFu + ((v.u >> 16) & 1u)) >> 16);
}
__device__ inline u32 pk2bf(float a, float b) {   // low16 = bf16(a)
    return (u32)f2bf(a) | ((u32)f2bf(b) << 16);
}
__device__ inline float bflo(u32 w) { return __uint_as_float(w << 16); }
__device__ inline float bfhi(u32 w) { return __uint_as_float(w & 0xFFFF0000u); }

// weight [O][C*9] fp32 -> wbf [O][KTOT] bf16, k' = g*KG + t*16 + cl
__global__ void wprep_kernel(const float* __restrict__ w, u16* __restrict__ wbf) {
    const int e = blockIdx.x * BDIM + threadIdx.x;    // < 163840
    const int o  = e / KTOT;
    const int kp = e - o * KTOT;
    const int g  = kp / KG;
    const int r  = kp - g * KG;
    const int t  = r >> 4;
    const int cl = r & 15;
    float v = 0.f;
    if (t < KK) v = w[o * (Cn * KK) + (g * CG + cl) * KK + t];
    wbf[e] = f2bf(v);
}

__global__ __launch_bounds__(BDIM, 4)
void dcn_mfma_kernel(const float* __restrict__ x,
                     const float* __restrict__ offs,
                     const float* __restrict__ mask,
                     const u16*   __restrict__ wbf,
                     const float* __restrict__ bias,
                     float* __restrict__ out)
{
    __shared__ __align__(16) u32 pband[8 * XSTP];  // 21,024 B
    __shared__ __align__(16) u16 ash[PXB * AST];   // 10,880 B (tot ~31.9 KB)

    const int tid    = threadIdx.x;
    const int b      = blockIdx.x & 7;          // batch<->XCD affinity
    const int rem    = blockIdx.x >> 3;
    const int h      = rem >> 1;
    const int pxbase = (rem & 1) * PXB;
    const int r0     = min(max(h - 4, 0), Hn - BANDH);

    // band task map: tau = tid + it*256 -> px4=tau&15, pair=(tau>>4)&7, row=tau>>7
    const int s_px4  = tid & 15;
    const int s_pair = (tid >> 4) & 7;
    float4 bnda[5], bndb[5];
    {   // issue granule-0 band loads early
        #pragma unroll
        for (int it = 0; it < 5; ++it) {
            const int row = (tid + it * BDIM) >> 7;
            const float* base = x + (((size_t)(b * Cn + 2 * s_pair)) << 12)
                                + (r0 + row) * Wn + (s_px4 << 2);
            bnda[it] = *(const float4*)base;
            bndb[it] = *(const float4*)(base + 4096);
        }
    }

    // ---- meta in registers: weights mw, coord code mq, band word index mi ----
    float4 mw[2]; int2 mq[2]; int2 mi[2];
    #pragma unroll
    for (int it = 0; it < 2; ++it) {
        mw[it] = make_float4(0.f, 0.f, 0.f, 0.f);
        mq[it] = make_int2(r0 << 8, r0 << 8);
        mi[it] = make_int2(7, 7);
        const int e = tid + it * BDIM;
        if (e < ME) {
            const int t = e >> 5, px = e & 31, pg = pxbase + px;
            const int ty = t / 3, tx = t - ty * 3;
            const float oy = offs[((b * 18 + 2 * t    ) * Hn + h) * Wn + pg];
            const float ox = offs[((b * 18 + 2 * t + 1) * Hn + h) * Wn + pg];
            const float m  = mask[((b * KK + t) * Hn + h) * Wn + pg];
            const float py = (float)(h - PAD + ty) + oy;
            const float qx = (float)(pg - PAD + tx) + ox;
            const float fy = floorf(py), fx = floorf(qx);
            const float wy1 = py - fy, wx1 = qx - fx;
            const float wy0 = 1.f - wy1, wx0 = 1.f - wx1;
            const int y0 = (int)fy, x0 = (int)fx;
            const bool cx0 = (x0 >= 0) && (x0 < Wn);
            const bool cx1 = (x0 >= -1) && (x0 < Wn - 1);
            const float wr[2] = { wy0, wy1 };
            float wout[4]; int qout[2], iout[2];
            #pragma unroll
            for (int j = 0; j < 2; ++j) {
                const int yr = y0 + j;
                const bool rv = (yr >= 0) && (yr < Hn);
                wout[2 * j]     = (rv && cx0) ? wr[j] * wx0 * m : 0.f;
                wout[2 * j + 1] = (rv && cx1) ? wr[j] * wx1 * m : 0.f;
                int qv;
                if (!rv || (!cx0 && !cx1)) qv = r0 << 8;   // junk: w=0, reads pad
                else                       qv = (yr << 8) | (x0 + 1);
                const bool inband = (qv >> 8) >= r0 && (qv >> 8) < r0 + BANDH;
                qout[j] = inband ? qv : ~qv;
                iout[j] = (((qv >> 8) - r0) << 6) + (qv & 255) + 7;  // word idx
            }
            mw[it] = make_float4(wout[0], wout[1], wout[2], wout[3]);
            mq[it] = make_int2(qout[0], qout[1]);
            mi[it] = make_int2(iout[0], iout[1]);
        }
    }

    // ---- write band 0; zero band pads; zero ash pad chunk ----
    {
        #pragma unroll
        for (int it = 0; it < 5; ++it) {
            const int row = (tid + it * BDIM) >> 7;
            u32* d = &pband[s_pair * XSTP + row * 64 + 8 + (s_px4 << 2)];
            d[0] = pk2bf(bnda[it].x, bndb[it].x);
            d[1] = pk2bf(bnda[it].y, bndb[it].y);
            d[2] = pk2bf(bnda[it].z, bndb[it].z);
            d[3] = pk2bf(bnda[it].w, bndb[it].w);
        }
        if (tid < 128) {   // zero lead/tail pads (staging never touches them)
            const int pr = tid >> 4, ws = tid & 15;
            pband[pr * XSTP + (ws < 8 ? ws : 640 + ws)] = 0;
        }
        ((u32*)ash)[(tid >> 3) * 85 + 72 + (tid & 7)] = 0;   // k=144..159 pad
    }
    __syncthreads();

    const int wv = tid >> 6, ln = tid & 63, quad = ln >> 4, l16 = ln & 15;
    const u16* wrow0 = wbf + (size_t)(wv * 32 + l16) * KTOT;

    f32x4 acc[2][2];
    #pragma unroll
    for (int mt = 0; mt < 2; ++mt)
        #pragma unroll
        for (int nt = 0; nt < 2; ++nt) acc[mt][nt] = (f32x4){0.f, 0.f, 0.f, 0.f};

    for (int g = 0; g < NG; ++g) {
        // ---- sampling: pband + meta -> ash ----
        #pragma unroll
        for (int it = 0; it < 2; ++it) {
            const int e = tid + it * BDIM;
            if (e < ME) {
                const int t = e >> 5, px = e & 31;
                const float4 w  = mw[it];
                const int2   q  = mq[it];
                const int2   ix = mi[it];
                u32 avp[8];
                if (!__any((q.x | q.y) < 0)) {   // all corners in band
                    #pragma unroll
                    for (int c2 = 0; c2 < 8; ++c2) {
                        const u32* pc = &pband[c2 * XSTP];
                        const u32 wt0 = pc[ix.x], wt1 = pc[ix.x + 1];
                        const u32 wb0 = pc[ix.y], wb1 = pc[ix.y + 1];
                        const float va = fmaf(w.x, bflo(wt0), fmaf(w.y, bflo(wt1),
                                         fmaf(w.z, bflo(wb0), w.w * bflo(wb1))));
                        const float vb = fmaf(w.x, bfhi(wt0), fmaf(w.y, bfhi(wt1),
                                         fmaf(w.z, bfhi(wb0), w.w * bfhi(wb1))));
                        avp[c2] = pk2bf(va, vb);
                    }
                } else {                          // rare: clamped global reads
                    const int qx = q.x < 0 ? ~q.x : q.x;
                    const int qy = q.y < 0 ? ~q.y : q.y;
                    const int yrx = qx >> 8, yry = qy >> 8;
                    const int xx = (qx & 255) - 1, xy = (qy & 255) - 1;
                    const int ax0 = max(xx, 0), ax1 = min(xx + 1, Wn - 1);
                    const int ay0 = max(xy, 0), ay1 = min(xy + 1, Wn - 1);
                    const float* gp = x + (((size_t)(b * Cn + g * CG)) << 12);
                    for (int c2 = 0; c2 < 8; ++c2) {
                        float v2[2];
                        for (int sb = 0; sb < 2; ++sb) {
                            const float* gc = gp + ((2 * c2 + sb) << 12);
                            const float t0 = gc[yrx * Wn + ax0], t1 = gc[yrx * Wn + ax1];
                            const float b0 = gc[yry * Wn + ay0], b1 = gc[yry * Wn + ay1];
                            v2[sb] = fmaf(w.x, t0, fmaf(w.y, t1,
                                     fmaf(w.z, b0, w.w * b1)));
                        }
                        avp[c2] = pk2bf(v2[0], v2[1]);
                    }
                }
                u32* d = (u32*)ash + px * 85 + t * 8;
                #pragma unroll
                for (int j = 0; j < 8; ++j) d[j] = avp[j];
            }
        }
        __syncthreads();

        // ---- issue next band's global loads (drain during MFMA) ----
        if (g + 1 < NG) {
            #pragma unroll
            for (int it = 0; it < 5; ++it) {
                const int row = (tid + it * BDIM) >> 7;
                const float* base = x + (((size_t)(b * Cn + (g + 1) * CG + 2 * s_pair)) << 12)
                                    + (r0 + row) * Wn + (s_px4 << 2);
                bnda[it] = *(const float4*)base;
                bndb[it] = *(const float4*)(base + 4096);
            }
        }

        // ---- MFMA: 5 K-steps of 32; A from L2 (wbf), B from ash (b32) ----
        const u32* ad = (const u32*)ash;
        #pragma unroll
        for (int s = 0; s < 5; ++s) {
            const int kg = g * KG + s * 32 + quad * 8;
            const bf16x8 a0 = *(const bf16x8*)(wrow0 + kg);
            const bf16x8 a1 = *(const bf16x8*)(wrow0 + 16 * KTOT + kg);
            union BF { bf16x8 v; u32 w[4]; } b0, b1;
            const int kd = s * 16 + quad * 4;
            #pragma unroll
            for (int j = 0; j < 4; ++j) {
                b0.w[j] = ad[(0 * 16 + l16) * 85 + kd + j];
                b1.w[j] = ad[(1 * 16 + l16) * 85 + kd + j];
            }
            acc[0][0] = __builtin_amdgcn_mfma_f32_16x16x32_bf16(a0, b0.v, acc[0][0], 0, 0, 0);
            acc[0][1] = __builtin_amdgcn_mfma_f32_16x16x32_bf16(a0, b1.v, acc[0][1], 0, 0, 0);
            acc[1][0] = __builtin_amdgcn_mfma_f32_16x16x32_bf16(a1, b0.v, acc[1][0], 0, 0, 0);
            acc[1][1] = __builtin_amdgcn_mfma_f32_16x16x32_bf16(a1, b1.v, acc[1][1], 0, 0, 0);
        }

        // ---- write next band into pband ----
        if (g + 1 < NG) {
            #pragma unroll
            for (int it = 0; it < 5; ++it) {
                const int row = (tid + it * BDIM) >> 7;
                u32* d = &pband[s_pair * XSTP + row * 64 + 8 + (s_px4 << 2)];
                d[0] = pk2bf(bnda[it].x, bndb[it].x);
                d[1] = pk2bf(bnda[it].y, bndb[it].y);
                d[2] = pk2bf(bnda[it].z, bndb[it].z);
                d[3] = pk2bf(bnda[it].w, bndb[it].w);
            }
        }
        __syncthreads();
    }

    // ---- epilogue: transpose via LDS (reuse pband) -> full-line stores ----
    float* tr = (float*)pband;           // 128 o x 32 px, stride 36
    #pragma unroll
    for (int mt = 0; mt < 2; ++mt)
        #pragma unroll
        for (int nt = 0; nt < 2; ++nt)
            #pragma unroll
            for (int r = 0; r < 4; ++r) {
                const int o  = wv * 32 + mt * 16 + quad * 4 + r;
                const int px = nt * 16 + l16;
                tr[o * 36 + px] = acc[mt][nt][r] + bias[o];
            }
    __syncthreads();
    float* ob = out + (size_t)b * On * Hn * Wn + h * Wn + pxbase;
    {
        const int orow = tid >> 3, ck = tid & 7;
        #pragma unroll
        for (int it = 0; it < 4; ++it) {
            const int o = it * 32 + orow;
            const float4 v = *(const float4*)&tr[o * 36 + (ck << 2)];
            *(float4*)&ob[(size_t)o * (Hn * Wn) + (ck << 2)] = v;
        }
    }
}

// ================= fallback: proven R2 fp32 kernel (no d_ws) =================
constexpr int FB_PXB = 32, FB_CCH = 4, FB_NCT = FB_CCH * KK, FB_MW = KK * FB_PXB;

#define FMA4(A, S, W)                          \
    A.x = fmaf((S).x, (W), A.x);               \
    A.y = fmaf((S).y, (W), A.y);               \
    A.z = fmaf((S).z, (W), A.z);               \
    A.w = fmaf((S).w, (W), A.w);

__global__ __launch_bounds__(BDIM, 4)
void dcn_fb_kernel(const float* __restrict__ x,
                   const float* __restrict__ offs,
                   const float* __restrict__ mask,
                   const float* __restrict__ weight,
                   const float* __restrict__ bias,
                   float* __restrict__ out)
{
    __shared__ float wmeta[4 * FB_MW];
    __shared__ int   imeta[4 * FB_MW];
    __shared__ float ssh[FB_NCT * FB_PXB];
    __shared__ float wsh[FB_NCT * On];

    const int tid    = threadIdx.x;
    const int b      = blockIdx.x & 7;
    const int rem    = blockIdx.x >> 3;
    const int h      = rem >> 1;
    const int pxbase = (rem & 1) * FB_PXB;

    for (int e = tid; e < FB_MW; e += BDIM) {
        const int t  = e >> 5;
        const int px = e & 31;
        const int pg = pxbase + px;
        const int ty = t / 3, tx = t - ty * 3;
        const float oy = offs[((b * 18 + 2 * t    ) * Hn + h) * Wn + pg];
        const float ox = offs[((b * 18 + 2 * t + 1) * Hn + h) * Wn + pg];
        const float m  = mask[((b * KK + t) * Hn + h) * Wn + pg];
        const float py = (float)(h - PAD + ty) + oy;
        const float qx = (float)(pg - PAD + tx) + ox;
        const float y0 = floorf(py), x0 = floorf(qx);
        const float wy1 = py - y0, wx1 = qx - x0;
        const float wy0 = 1.f - wy1, wx0 = 1.f - wx1;
        const float cw[4] = { wy0 * wx0, wy0 * wx1, wy1 * wx0, wy1 * wx1 };
        #pragma unroll
        for (int k = 0; k < 4; ++k) {
            const float yk = y0 + (float)(k >> 1);
            const float xk = x0 + (float)(k & 1);
            const bool valid = (yk >= 0.f) && (yk <= (float)(Hn - 1)) &&
                               (xk >= 0.f) && (xk <= (float)(Wn - 1));
            const int yc = (int)fminf(fmaxf(yk, 0.f), (float)(Hn - 1));
            const int xc = (int)fminf(fmaxf(xk, 0.f), (float)(Wn - 1));
            wmeta[k * FB_MW + e] = valid ? cw[k] * m : 0.f;
            imeta[k * FB_MW + e] = yc * Wn + xc;
        }
    }
    __syncthreads();

    const int px0 = (tid & 7) << 2;
    const int oo  = (tid >> 3) << 2;

    float4 acc[4];
    #pragma unroll
    for (int j = 0; j < 4; ++j) acc[j] = make_float4(0.f, 0.f, 0.f, 0.f);

    for (int cb = 0; cb < Cn / FB_CCH; ++cb) {
        #pragma unroll
        for (int it = 0; it < (FB_NCT * On) / BDIM; ++it) {
            const int e = tid + it * BDIM;
            const int r = e >> 7;
            const int o = e & 127;
            wsh[r * On + o] = weight[o * (Cn * KK) + cb * FB_NCT + r];
        }
        for (int e = tid; e < FB_NCT * FB_PXB; e += BDIM) {
            const int px = e & 31;
            const int ct = e >> 5;
            const int c  = ct / 9;
            const int mb = (ct - c * 9) * FB_PXB + px;
            const float* xp = x + (((b * Cn) + cb * FB_CCH + c) << 12);
            float v =  wmeta[mb]              * xp[imeta[mb]];
            v = fmaf(wmeta[FB_MW     + mb], xp[imeta[FB_MW     + mb]], v);
            v = fmaf(wmeta[2 * FB_MW + mb], xp[imeta[2 * FB_MW + mb]], v);
            v = fmaf(wmeta[3 * FB_MW + mb], xp[imeta[3 * FB_MW + mb]], v);
            ssh[ct * FB_PXB + px] = v;
        }
        __syncthreads();

        #pragma unroll 6
        for (int ct = 0; ct < FB_NCT; ++ct) {
            const float4 sv = *(const float4*)&ssh[ct * FB_PXB + px0];
            const float4 wa = *(const float4*)&wsh[ct * On + oo];
            FMA4(acc[0], sv, wa.x);
            FMA4(acc[1], sv, wa.y);
            FMA4(acc[2], sv, wa.z);
            FMA4(acc[3], sv, wa.w);
        }
        __syncthreads();
    }

    #pragma unroll
    for (int j = 0; j < 4; ++j) {
        const float bv = bias[oo + j];
        float4 r = acc[j];
        r.x += bv; r.y += bv; r.z += bv; r.w += bv;
        *(float4*)&out[((b * On + oo + j) * Hn + h) * Wn + pxbase + px0] = r;
    }
}

extern "C" void kernel_launch(void* const* d_in, const int* in_sizes, int n_in,
                              void* d_out, int out_size, void* d_ws, size_t ws_size,
                              hipStream_t stream) {
    const float* x      = (const float*)d_in[0];
    const float* offs   = (const float*)d_in[1];
    const float* mask   = (const float*)d_in[2];
    const float* weight = (const float*)d_in[3];
    const float* bias   = (const float*)d_in[4];
    float* out = (float*)d_out;

    const size_t need = (size_t)On * KTOT * sizeof(u16);   // 327,680 B
    if (d_ws != nullptr && ws_size >= need) {
        u16* wbf = (u16*)d_ws;
        wprep_kernel<<<dim3(On * KTOT / BDIM), dim3(BDIM), 0, stream>>>(weight, wbf);
        dcn_mfma_kernel<<<dim3(Bn * Hn * 2), dim3(BDIM), 0, stream>>>(
            x, offs, mask, wbf, bias, out);
    } else {
        dcn_fb_kernel<<<dim3(Bn * Hn * 2), dim3(BDIM), 0, stream>>>(
            x, offs, mask, weight, bias, out);
    }
}